// Round 9
// baseline (216.115 us; speedup 1.0000x reference)
//
#include <hip/hip_runtime.h>
#include <math.h>

#define N_NODES 100000
#define N_EDGES 1600000
#define D_FEAT 32
#define D_HID 64
#define D_OUT 64
#define CAP 48          // per-node slot capacity; deg ~ Poisson(16), safe
#define NPB 32          // nodes per coarse bucket (1<<5); 3125*32 = 100000 exact
#define NBKT 3125       // N_NODES / NPB
#define B1 256          // sort blocks; each owns a dense 6250-entry segment
#define E_PER_B1 6250   // 256 * 6250 = 1.6M edges exactly
#define NB_NODE 1024    // node-precompute blocks
#define AGG_B 2048      // persistent agg blocks: 8/CU = 32-wave cap

typedef _Float16 half8 __attribute__((ext_vector_type(8)));
typedef float f32x4  __attribute__((ext_vector_type(4)));

// packed f16 relu(v + (-q)) on a channel pair, guaranteed lowering:
// exactly one v_pk_add_f16 + one v_pk_max_f16.
__device__ inline unsigned pk_subrelu(unsigned v, unsigned nq) {
    unsigned r;
    asm("v_pk_add_f16 %0, %1, %2\n\t"
        "v_pk_max_f16 %0, %0, 0"
        : "=v"(r) : "v"(v), "v"(nq));
    return r;
}

// ---------------------------------------------------------------------------
// Kernel 1: per-node precompute (f32 math, f16 store, q stored NEGATED).
//   q[n][k] = pos[n] @ W1[32:35];  v[n][k] = b1[k] + x[n] @ W1[:32] + q[n][k]
// per-edge layer-1 output = relu(v[src] + nq[dst]).
// ---------------------------------------------------------------------------
__global__ __launch_bounds__(256)
void node_kernel(const float* __restrict__ x,
                 const float* __restrict__ pos,
                 const float* __restrict__ W1,
                 const float* __restrict__ b1,
                 unsigned short* __restrict__ vb,
                 unsigned short* __restrict__ qb) {
    const int lane = threadIdx.x & 63;
    const int wid  = (blockIdx.x * blockDim.x + threadIdx.x) >> 6;
    const int nw   = (NB_NODE * 256) >> 6;

    float w[D_FEAT + 3];
#pragma unroll
    for (int f = 0; f < D_FEAT + 3; ++f)
        w[f] = W1[f * D_HID + lane];
    const float bb = b1[lane];

    for (int node = wid; node < N_NODES; node += nw) {
        const float* xr = x + (size_t)node * D_FEAT;
        float acc = bb;
#pragma unroll
        for (int f = 0; f < D_FEAT; ++f)
            acc = fmaf(xr[f], w[f], acc);

        const float* pr = pos + (size_t)node * 3;
        float qa = 0.0f;
#pragma unroll
        for (int p = 0; p < 3; ++p)
            qa = fmaf(pr[p], w[D_FEAT + p], qa);

        vb[(size_t)node * D_HID + lane] =
            __builtin_bit_cast(unsigned short, (_Float16)(acc + qa));
        qb[(size_t)node * D_HID + lane] =
            __builtin_bit_cast(unsigned short, (_Float16)(-qa));
    }
}

// ---------------------------------------------------------------------------
// Kernel 2: dense local counting sort (R8 structure unchanged) + block 0
// additionally builds W2T: f16 transposed W2 (W2T[n][k]) so agg's B-fragment
// load is 8x16B vector loads per thread instead of 64 scalar f32 loads
// (the R8 lesson: per-block W2 prologue x3125 blocks was a VMEM-issue wall).
// Entry packing: (src << 5) | (dst & 31).
// ---------------------------------------------------------------------------
__global__ __launch_bounds__(1024)
void sort_kernel(const int* __restrict__ src,
                 const int* __restrict__ dst,
                 unsigned int* __restrict__ coarse,
                 int* __restrict__ dirT,
                 const float* __restrict__ W2,
                 unsigned short* __restrict__ W2T) {
    __shared__ int hist[NBKT];       // 12.5 KB: counts -> starts -> cursors
    __shared__ int stage[E_PER_B1];  // 25 KB
    __shared__ int wsum[16];

    const int tid  = threadIdx.x;
    const int lane = tid & 63;
    const int wv   = tid >> 6;       // 0..15
    const int e0   = blockIdx.x * E_PER_B1;

    if (blockIdx.x == 0) {           // f16 transpose of W2 (16 KB, L2-hot)
        for (int i = tid; i < D_HID * D_OUT; i += 1024) {
            float w = W2[i];                      // i = k*64 + n
            W2T[(size_t)(i & 63) * D_HID + (i >> 6)] =
                __builtin_bit_cast(unsigned short, (_Float16)w);
        }
    }

    for (int b = tid; b < NBKT; b += 1024) hist[b] = 0;
    __syncthreads();

    for (int e = e0 + tid; e < e0 + E_PER_B1; e += 1024)
        atomicAdd(&hist[dst[e] >> 5], 1);
    __syncthreads();

    // ---- exclusive scan of hist (3125) in place: 4 elems/thread ----
    const int i0 = tid * 4;
    int c[4];
    int sum = 0;
#pragma unroll
    for (int k = 0; k < 4; ++k) {
        c[k] = (i0 + k < NBKT) ? hist[i0 + k] : 0;
        sum += c[k];
    }
    int inc = sum;                       // wave-inclusive scan of chunk sums
#pragma unroll
    for (int d = 1; d < 64; d <<= 1) {
        int u = __shfl_up(inc, d, 64);
        if (lane >= d) inc += u;
    }
    if (lane == 63) wsum[wv] = inc;      // wave totals
    __syncthreads();
    if (wv == 0) {
        int s = (lane < 16) ? wsum[lane] : 0;
#pragma unroll
        for (int d = 1; d < 16; d <<= 1) {
            int u = __shfl_up(s, d, 64);
            if (lane >= d) s += u;
        }
        if (lane < 16) wsum[lane] = s;   // inclusive wave prefix
    }
    __syncthreads();
    int excl = inc - sum + ((wv > 0) ? wsum[wv - 1] : 0);
#pragma unroll
    for (int k = 0; k < 4; ++k) {
        if (i0 + k < NBKT) hist[i0 + k] = excl;   // own slots only: no race
        excl += c[k];
    }
    __syncthreads();

    // ---- transposed directory: absolute start of each bucket's segment
    for (int b = tid; b < NBKT; b += 1024)
        dirT[(size_t)b * B1 + blockIdx.x] = e0 + hist[b];
    __syncthreads();                     // dir written before cursors move

    // ---- placement via LDS cursors into LDS staging ----
    for (int e = e0 + tid; e < e0 + E_PER_B1; e += 1024) {
        int d = dst[e], s = src[e];
        int p = atomicAdd(&hist[d >> 5], 1);   // p in [0, 6250) by construction
        stage[p] = (int)(((unsigned)s << 5) | (unsigned)(d & 31));
    }
    __syncthreads();

    // ---- dense, full-line copy-out ----
    for (int i = tid; i < E_PER_B1; i += 1024)
        coarse[e0 + i] = (unsigned)stage[i];
}

// ---------------------------------------------------------------------------
// Kernel 3: PERSISTENT fused fine-bucketing + per-node MFMA aggregation.
// R8 lesson: per-bucket prologue (64 scalar W2 loads/thread) x 3125 blocks
// was the dominant cost (6.1 us CU-time per 32-node block). Now: 2048
// persistent blocks (8/CU = 32-wave cap), prologue ONCE per block (8x16B
// vector loads from prebuilt f16 W2T), buckets claimed via global atomic
// work-stealing (perfect load balance, no dispatch ramp). Per bucket:
// zero lcnt -> segment walk into LDS slot lists -> 8 nodes/wave aggregation
// (packed-f16 afrag, 4x2 mfma_f32_16x16x32_f16, register max, coalesced
// store). Padding rows use src = i (self-loop, idempotent under max).
// ---------------------------------------------------------------------------
__global__ __launch_bounds__(256)
void agg_kernel(const unsigned short* __restrict__ vb,
                const unsigned short* __restrict__ qb,
                const unsigned short* __restrict__ W2T,
                const float* __restrict__ b2,
                const int* __restrict__ dirT,
                const unsigned int* __restrict__ coarse,
                int* __restrict__ ctr,
                float* __restrict__ out) {
    __shared__ int lcnt[NPB];
    __shared__ int lslots[NPB][CAP];
    __shared__ int sbkt;

    const int tid  = threadIdx.x;
    const int lane = tid & 63;
    const int wave = tid >> 6;             // 0..3
    const int quad = lane >> 4;
    const int mrow = lane & 15;

    // B fragments: one 16B vector load each from W2T[n][k]
    half8 bfrag[4][2];
#pragma unroll
    for (int t = 0; t < 4; ++t)
#pragma unroll
        for (int kh = 0; kh < 2; ++kh)
            bfrag[t][kh] = *(const half8*)(W2T + (size_t)(t * 16 + mrow) * D_HID
                                               + kh * 32 + quad * 8);
    float bias[4];
#pragma unroll
    for (int t = 0; t < 4; ++t) bias[t] = b2[t * 16 + mrow];

    while (true) {
        if (tid == 0) sbkt = atomicAdd(ctr, 1);
        __syncthreads();
        const int bkt = sbkt;              // uniform
        if (bkt >= NBKT) break;
        const int nbase = bkt << 5;

        for (int i = tid; i < NPB; i += 256) lcnt[i] = 0;
        __syncthreads();

        // fine bucketing: thread t walks sort-block t's segment (dense dirT rows)
        {
            const int s0 = dirT[(size_t)bkt * B1 + tid];
            const int s1 = (bkt + 1 < NBKT) ? dirT[(size_t)(bkt + 1) * B1 + tid]
                                            : (tid + 1) * E_PER_B1;
            for (int j = s0; j < s1; ++j) {
                unsigned enc = coarse[j];
                int local = (int)(enc & 31u);
                int s     = (int)(enc >> 5);
                int p = atomicAdd(&lcnt[local], 1);
                if (p < CAP) lslots[local][p] = s;
            }
        }
        __syncthreads();

        // per-node aggregation, 8 nodes per wave
        for (int ln = wave; ln < NPB; ln += 4) {
            const int node = nbase + ln;   // 3125*32 == N_NODES: no bound check

            const uint4 nq0 = *(const uint4*)(qb + (size_t)node * D_HID + quad * 8);
            const uint4 nq1 = *(const uint4*)(qb + (size_t)node * D_HID + 32 + quad * 8);

            int deg = lcnt[ln];
            if (deg > CAP) deg = CAP;
            const int rows = deg + 1;          // + self-loop
            const int nbat = (rows + 15) >> 4;

            float rmax[4][4];
#pragma unroll
            for (int t = 0; t < 4; ++t)
#pragma unroll
                for (int r = 0; r < 4; ++r) rmax[t][r] = -INFINITY;

            for (int b = 0; b < nbat; ++b) {
                int idx = b * 16 + mrow;
                int idxc = (idx < CAP) ? idx : (CAP - 1);    // clamp LDS read
                int s = (idx < deg) ? lslots[ln][idxc] : node;

                const uint4 v0 = *(const uint4*)(vb + (size_t)s * D_HID + quad * 8);
                const uint4 v1 = *(const uint4*)(vb + (size_t)s * D_HID + 32 + quad * 8);

                uint4 a0u, a1u;
                a0u.x = pk_subrelu(v0.x, nq0.x);
                a0u.y = pk_subrelu(v0.y, nq0.y);
                a0u.z = pk_subrelu(v0.z, nq0.z);
                a0u.w = pk_subrelu(v0.w, nq0.w);
                a1u.x = pk_subrelu(v1.x, nq1.x);
                a1u.y = pk_subrelu(v1.y, nq1.y);
                a1u.z = pk_subrelu(v1.z, nq1.z);
                a1u.w = pk_subrelu(v1.w, nq1.w);
                half8 a0 = __builtin_bit_cast(half8, a0u);
                half8 a1 = __builtin_bit_cast(half8, a1u);

#pragma unroll
                for (int t = 0; t < 4; ++t) {
                    f32x4 acc = (f32x4){0.f, 0.f, 0.f, 0.f};
                    acc = __builtin_amdgcn_mfma_f32_16x16x32_f16(a0, bfrag[t][0], acc, 0, 0, 0);
                    acc = __builtin_amdgcn_mfma_f32_16x16x32_f16(a1, bfrag[t][1], acc, 0, 0, 0);
#pragma unroll
                    for (int r = 0; r < 4; ++r)
                        rmax[t][r] = fmaxf(rmax[t][r], acc[r]);
                }
            }

            float fin[4];
#pragma unroll
            for (int t = 0; t < 4; ++t) {
                float m = fmaxf(fmaxf(rmax[t][0], rmax[t][1]), fmaxf(rmax[t][2], rmax[t][3]));
                m = fmaxf(m, __shfl_xor(m, 16, 64));
                m = fmaxf(m, __shfl_xor(m, 32, 64));
                fin[t] = m + bias[t];
            }
            float r = (quad == 0) ? fin[0] : (quad == 1) ? fin[1] : (quad == 2) ? fin[2] : fin[3];
            out[(size_t)node * D_OUT + lane] = r;
        }
        __syncthreads();   // protect lcnt/lslots/sbkt before next iteration
    }
}

// ---------------------------------------------------------------------------
extern "C" void kernel_launch(void* const* d_in, const int* in_sizes, int n_in,
                              void* d_out, int out_size, void* d_ws, size_t ws_size,
                              hipStream_t stream) {
    const float* x   = (const float*)d_in[0];
    const float* pos = (const float*)d_in[1];
    const int*   ei  = (const int*)d_in[2];   // [2][N_EDGES]: row0=src, row1=dst
    const float* W1  = (const float*)d_in[3];
    const float* b1  = (const float*)d_in[4];
    const float* W2  = (const float*)d_in[5];
    const float* b2  = (const float*)d_in[6];
    float* out = (float*)d_out;

    char* ws = (char*)d_ws;
    unsigned short* vb   = (unsigned short*)ws;                     // 12.8 MB (f16 v)
    unsigned short* qb   = (unsigned short*)(ws + 12800000);        // 12.8 MB (f16 -q)
    unsigned int* coarse = (unsigned int*)(ws + 25600000);          // 6.4 MB
    int*            dirT = (int*)(ws + 32000000);                   // 3.2 MB
    unsigned short* W2T  = (unsigned short*)(ws + 35200000);        // 8 KB (f16, transposed)
    int*            ctr  = (int*)(ws + 35208192);                   // 4 B

    const int* src = ei;
    const int* dst = ei + N_EDGES;

    (void)hipMemsetAsync(ctr, 0, sizeof(int), stream);
    hipLaunchKernelGGL(sort_kernel, dim3(B1), dim3(1024), 0, stream,
                       src, dst, coarse, dirT, W2, W2T);
    hipLaunchKernelGGL(node_kernel, dim3(NB_NODE), dim3(256), 0, stream,
                       x, pos, W1, b1, vb, qb);
    hipLaunchKernelGGL(agg_kernel, dim3(AGG_B), dim3(256), 0, stream,
                       vb, qb, W2T, b2, dirT, coarse, ctr, out);
}

// Round 10
// 199.665 us; speedup vs baseline: 1.0824x; 1.0824x over previous
//
#include <hip/hip_runtime.h>
#include <math.h>

#define N_NODES 100000
#define N_EDGES 1600000
#define D_FEAT 32
#define D_HID 64
#define D_OUT 64
#define CAP 48          // per-node slot capacity; deg ~ Poisson(16), safe
#define NPB 32          // nodes per coarse bucket (1<<5); 3125*32 = 100000 exact
#define NBKT 3125       // N_NODES / NPB
#define B1 256          // sort blocks; each owns a dense 6250-entry segment
#define E_PER_B1 6250   // 256 * 6250 = 1.6M edges exactly
#define NB_NODE 1024    // node-precompute blocks

typedef _Float16 half8 __attribute__((ext_vector_type(8)));
typedef float f32x4  __attribute__((ext_vector_type(4)));

// packed f16 relu(v + (-q)) on a channel pair, guaranteed lowering:
// exactly one v_pk_add_f16 + one v_pk_max_f16.
__device__ inline unsigned pk_subrelu(unsigned v, unsigned nq) {
    unsigned r;
    asm("v_pk_add_f16 %0, %1, %2\n\t"
        "v_pk_max_f16 %0, %0, 0"
        : "=v"(r) : "v"(v), "v"(nq));
    return r;
}

// ---------------------------------------------------------------------------
// Kernel 1: per-node precompute (f32 math, f16 store, q stored NEGATED).
//   q[n][k] = pos[n] @ W1[32:35];  v[n][k] = b1[k] + x[n] @ W1[:32] + q[n][k]
// per-edge layer-1 output = relu(v[src] + nq[dst]).
// ---------------------------------------------------------------------------
__global__ __launch_bounds__(256)
void node_kernel(const float* __restrict__ x,
                 const float* __restrict__ pos,
                 const float* __restrict__ W1,
                 const float* __restrict__ b1,
                 unsigned short* __restrict__ vb,
                 unsigned short* __restrict__ qb) {
    const int lane = threadIdx.x & 63;
    const int wid  = (blockIdx.x * blockDim.x + threadIdx.x) >> 6;
    const int nw   = (NB_NODE * 256) >> 6;

    float w[D_FEAT + 3];
#pragma unroll
    for (int f = 0; f < D_FEAT + 3; ++f)
        w[f] = W1[f * D_HID + lane];
    const float bb = b1[lane];

    for (int node = wid; node < N_NODES; node += nw) {
        const float* xr = x + (size_t)node * D_FEAT;
        float acc = bb;
#pragma unroll
        for (int f = 0; f < D_FEAT; ++f)
            acc = fmaf(xr[f], w[f], acc);

        const float* pr = pos + (size_t)node * 3;
        float qa = 0.0f;
#pragma unroll
        for (int p = 0; p < 3; ++p)
            qa = fmaf(pr[p], w[D_FEAT + p], qa);

        vb[(size_t)node * D_HID + lane] =
            __builtin_bit_cast(unsigned short, (_Float16)(acc + qa));
        qb[(size_t)node * D_HID + lane] =
            __builtin_bit_cast(unsigned short, (_Float16)(-qa));
    }
}

// ---------------------------------------------------------------------------
// Kernel 2: dense local counting sort (R8 structure) + block 0 builds W2T:
// f16 transposed W2 (W2T[n][k]) so agg's B-fragment load is 8x16B vector
// loads per thread instead of 64 scalar f32 loads.
// Entry packing: (src << 5) | (dst & 31).
// ---------------------------------------------------------------------------
__global__ __launch_bounds__(1024)
void sort_kernel(const int* __restrict__ src,
                 const int* __restrict__ dst,
                 unsigned int* __restrict__ coarse,
                 int* __restrict__ dirT,
                 const float* __restrict__ W2,
                 unsigned short* __restrict__ W2T) {
    __shared__ int hist[NBKT];       // 12.5 KB: counts -> starts -> cursors
    __shared__ int stage[E_PER_B1];  // 25 KB
    __shared__ int wsum[16];

    const int tid  = threadIdx.x;
    const int lane = tid & 63;
    const int wv   = tid >> 6;       // 0..15
    const int e0   = blockIdx.x * E_PER_B1;

    if (blockIdx.x == 0) {           // f16 transpose of W2 (16 KB, L2-hot)
        for (int i = tid; i < D_HID * D_OUT; i += 1024) {
            float w = W2[i];                      // i = k*64 + n
            W2T[(size_t)(i & 63) * D_HID + (i >> 6)] =
                __builtin_bit_cast(unsigned short, (_Float16)w);
        }
    }

    for (int b = tid; b < NBKT; b += 1024) hist[b] = 0;
    __syncthreads();

    for (int e = e0 + tid; e < e0 + E_PER_B1; e += 1024)
        atomicAdd(&hist[dst[e] >> 5], 1);
    __syncthreads();

    // ---- exclusive scan of hist (3125) in place: 4 elems/thread ----
    const int i0 = tid * 4;
    int c[4];
    int sum = 0;
#pragma unroll
    for (int k = 0; k < 4; ++k) {
        c[k] = (i0 + k < NBKT) ? hist[i0 + k] : 0;
        sum += c[k];
    }
    int inc = sum;                       // wave-inclusive scan of chunk sums
#pragma unroll
    for (int d = 1; d < 64; d <<= 1) {
        int u = __shfl_up(inc, d, 64);
        if (lane >= d) inc += u;
    }
    if (lane == 63) wsum[wv] = inc;      // wave totals
    __syncthreads();
    if (wv == 0) {
        int s = (lane < 16) ? wsum[lane] : 0;
#pragma unroll
        for (int d = 1; d < 16; d <<= 1) {
            int u = __shfl_up(s, d, 64);
            if (lane >= d) s += u;
        }
        if (lane < 16) wsum[lane] = s;   // inclusive wave prefix
    }
    __syncthreads();
    int excl = inc - sum + ((wv > 0) ? wsum[wv - 1] : 0);
#pragma unroll
    for (int k = 0; k < 4; ++k) {
        if (i0 + k < NBKT) hist[i0 + k] = excl;   // own slots only: no race
        excl += c[k];
    }
    __syncthreads();

    // ---- transposed directory: absolute start of each bucket's segment
    for (int b = tid; b < NBKT; b += 1024)
        dirT[(size_t)b * B1 + blockIdx.x] = e0 + hist[b];
    __syncthreads();                     // dir written before cursors move

    // ---- placement via LDS cursors into LDS staging ----
    for (int e = e0 + tid; e < e0 + E_PER_B1; e += 1024) {
        int d = dst[e], s = src[e];
        int p = atomicAdd(&hist[d >> 5], 1);   // p in [0, 6250) by construction
        stage[p] = (int)(((unsigned)s << 5) | (unsigned)(d & 31));
    }
    __syncthreads();

    // ---- dense, full-line copy-out ----
    for (int i = tid; i < E_PER_B1; i += 1024)
        coarse[e0 + i] = (unsigned)stage[i];
}

// ---------------------------------------------------------------------------
// Kernel 3: fused fine-bucketing + per-node MFMA aggregation (R8 dispatch:
// 3125 blocks — R9 lesson: persistent work-stealing regressed 74->92us).
// R9's counter story (dur insensitive to VALU/occupancy changes, VALU 47%
// / MFMA 10% at ~2-3 waves/SIMD) fits a per-batch latency chain: LDS slot
// read -> 2 dependent v-gathers (~500cy) -> compute. Fix = raise per-wave
// MLP: since P(deg>31)~3e-4, the <=2-batch fast path reads BOTH batches'
// slot indices first, then issues ALL SIX 16B loads (nq x2, vA x2, vB x2)
// before any compute: one load-round per node instead of 2-3, with 6
// outstanding loads instead of 2. Batches >=2 fall back to the old loop.
// Padding rows use src = i (self-loop, idempotent under max).
// ---------------------------------------------------------------------------
__global__ __launch_bounds__(256)
void agg_kernel(const unsigned short* __restrict__ vb,
                const unsigned short* __restrict__ qb,
                const unsigned short* __restrict__ W2T,
                const float* __restrict__ b2,
                const int* __restrict__ dirT,
                const unsigned int* __restrict__ coarse,
                float* __restrict__ out) {
    __shared__ int lcnt[NPB];
    __shared__ int lslots[NPB][CAP];

    const int tid  = threadIdx.x;
    const int lane = tid & 63;
    const int wave = tid >> 6;             // 0..3
    const int quad = lane >> 4;
    const int mrow = lane & 15;
    const int bkt  = blockIdx.x;
    const int nbase = bkt << 5;

    // B fragments: one 16B vector load each from W2T[n][k]
    half8 bfrag[4][2];
#pragma unroll
    for (int t = 0; t < 4; ++t)
#pragma unroll
        for (int kh = 0; kh < 2; ++kh)
            bfrag[t][kh] = *(const half8*)(W2T + (size_t)(t * 16 + mrow) * D_HID
                                               + kh * 32 + quad * 8);
    float bias[4];
#pragma unroll
    for (int t = 0; t < 4; ++t) bias[t] = b2[t * 16 + mrow];

    // fine bucketing into LDS: thread t walks sort-block t's segment.
    for (int i = tid; i < NPB; i += 256) lcnt[i] = 0;
    __syncthreads();
    {
        const int s0 = dirT[(size_t)bkt * B1 + tid];
        const int s1 = (bkt + 1 < NBKT) ? dirT[(size_t)(bkt + 1) * B1 + tid]
                                        : (tid + 1) * E_PER_B1;
        for (int j = s0; j < s1; ++j) {
            unsigned enc = coarse[j];
            int local = (int)(enc & 31u);
            int s     = (int)(enc >> 5);
            int p = atomicAdd(&lcnt[local], 1);
            if (p < CAP) lslots[local][p] = s;
        }
    }
    __syncthreads();

    // per-node aggregation, 8 nodes per wave
    for (int ln = wave; ln < NPB; ln += 4) {
        const int node = nbase + ln;       // 3125*32 == N_NODES: no bound check

        int deg = lcnt[ln];
        if (deg > CAP) deg = CAP;
        const int rows = deg + 1;              // + self-loop
        const int nbat = (rows + 15) >> 4;

        // --- fast-path upfront issue: slots first (LDS), then 6 VMEM loads
        const int idx0 = mrow;                 // batch A row, always < CAP
        const int idx1 = 16 + mrow;            // batch B row, 31 < CAP
        const int sA = (idx0 < deg) ? lslots[ln][idx0] : node;
        const int sB = (idx1 < deg) ? lslots[ln][idx1] : node;

        const uint4 nq0 = *(const uint4*)(qb + (size_t)node * D_HID + quad * 8);
        const uint4 nq1 = *(const uint4*)(qb + (size_t)node * D_HID + 32 + quad * 8);
        const uint4 vA0 = *(const uint4*)(vb + (size_t)sA * D_HID + quad * 8);
        const uint4 vA1 = *(const uint4*)(vb + (size_t)sA * D_HID + 32 + quad * 8);
        const uint4 vB0 = *(const uint4*)(vb + (size_t)sB * D_HID + quad * 8);
        const uint4 vB1 = *(const uint4*)(vb + (size_t)sB * D_HID + 32 + quad * 8);

        float rmax[4][4];
#pragma unroll
        for (int t = 0; t < 4; ++t)
#pragma unroll
            for (int r = 0; r < 4; ++r) rmax[t][r] = -INFINITY;

        // --- batch A ---
        {
            uint4 a0u, a1u;
            a0u.x = pk_subrelu(vA0.x, nq0.x);
            a0u.y = pk_subrelu(vA0.y, nq0.y);
            a0u.z = pk_subrelu(vA0.z, nq0.z);
            a0u.w = pk_subrelu(vA0.w, nq0.w);
            a1u.x = pk_subrelu(vA1.x, nq1.x);
            a1u.y = pk_subrelu(vA1.y, nq1.y);
            a1u.z = pk_subrelu(vA1.z, nq1.z);
            a1u.w = pk_subrelu(vA1.w, nq1.w);
            half8 a0 = __builtin_bit_cast(half8, a0u);
            half8 a1 = __builtin_bit_cast(half8, a1u);
#pragma unroll
            for (int t = 0; t < 4; ++t) {
                f32x4 acc = (f32x4){0.f, 0.f, 0.f, 0.f};
                acc = __builtin_amdgcn_mfma_f32_16x16x32_f16(a0, bfrag[t][0], acc, 0, 0, 0);
                acc = __builtin_amdgcn_mfma_f32_16x16x32_f16(a1, bfrag[t][1], acc, 0, 0, 0);
#pragma unroll
                for (int r = 0; r < 4; ++r)
                    rmax[t][r] = fmaxf(rmax[t][r], acc[r]);
            }
        }

        // --- batch B (only if the node has >16 rows) ---
        if (nbat > 1) {
            uint4 a0u, a1u;
            a0u.x = pk_subrelu(vB0.x, nq0.x);
            a0u.y = pk_subrelu(vB0.y, nq0.y);
            a0u.z = pk_subrelu(vB0.z, nq0.z);
            a0u.w = pk_subrelu(vB0.w, nq0.w);
            a1u.x = pk_subrelu(vB1.x, nq1.x);
            a1u.y = pk_subrelu(vB1.y, nq1.y);
            a1u.z = pk_subrelu(vB1.z, nq1.z);
            a1u.w = pk_subrelu(vB1.w, nq1.w);
            half8 a0 = __builtin_bit_cast(half8, a0u);
            half8 a1 = __builtin_bit_cast(half8, a1u);
#pragma unroll
            for (int t = 0; t < 4; ++t) {
                f32x4 acc = (f32x4){0.f, 0.f, 0.f, 0.f};
                acc = __builtin_amdgcn_mfma_f32_16x16x32_f16(a0, bfrag[t][0], acc, 0, 0, 0);
                acc = __builtin_amdgcn_mfma_f32_16x16x32_f16(a1, bfrag[t][1], acc, 0, 0, 0);
#pragma unroll
                for (int r = 0; r < 4; ++r)
                    rmax[t][r] = fmaxf(rmax[t][r], acc[r]);
            }
        }

        // --- rare tail: deg >= 32 (P ~ 3e-4) ---
        for (int b = 2; b < nbat; ++b) {
            int idx = b * 16 + mrow;
            int idxc = (idx < CAP) ? idx : (CAP - 1);    // clamp LDS read
            int s = (idx < deg) ? lslots[ln][idxc] : node;

            const uint4 v0 = *(const uint4*)(vb + (size_t)s * D_HID + quad * 8);
            const uint4 v1 = *(const uint4*)(vb + (size_t)s * D_HID + 32 + quad * 8);

            uint4 a0u, a1u;
            a0u.x = pk_subrelu(v0.x, nq0.x);
            a0u.y = pk_subrelu(v0.y, nq0.y);
            a0u.z = pk_subrelu(v0.z, nq0.z);
            a0u.w = pk_subrelu(v0.w, nq0.w);
            a1u.x = pk_subrelu(v1.x, nq1.x);
            a1u.y = pk_subrelu(v1.y, nq1.y);
            a1u.z = pk_subrelu(v1.z, nq1.z);
            a1u.w = pk_subrelu(v1.w, nq1.w);
            half8 a0 = __builtin_bit_cast(half8, a0u);
            half8 a1 = __builtin_bit_cast(half8, a1u);

#pragma unroll
            for (int t = 0; t < 4; ++t) {
                f32x4 acc = (f32x4){0.f, 0.f, 0.f, 0.f};
                acc = __builtin_amdgcn_mfma_f32_16x16x32_f16(a0, bfrag[t][0], acc, 0, 0, 0);
                acc = __builtin_amdgcn_mfma_f32_16x16x32_f16(a1, bfrag[t][1], acc, 0, 0, 0);
#pragma unroll
                for (int r = 0; r < 4; ++r)
                    rmax[t][r] = fmaxf(rmax[t][r], acc[r]);
            }
        }

        float fin[4];
#pragma unroll
        for (int t = 0; t < 4; ++t) {
            float m = fmaxf(fmaxf(rmax[t][0], rmax[t][1]), fmaxf(rmax[t][2], rmax[t][3]));
            m = fmaxf(m, __shfl_xor(m, 16, 64));
            m = fmaxf(m, __shfl_xor(m, 32, 64));
            fin[t] = m + bias[t];
        }
        float r = (quad == 0) ? fin[0] : (quad == 1) ? fin[1] : (quad == 2) ? fin[2] : fin[3];
        out[(size_t)node * D_OUT + lane] = r;
    }
}

// ---------------------------------------------------------------------------
extern "C" void kernel_launch(void* const* d_in, const int* in_sizes, int n_in,
                              void* d_out, int out_size, void* d_ws, size_t ws_size,
                              hipStream_t stream) {
    const float* x   = (const float*)d_in[0];
    const float* pos = (const float*)d_in[1];
    const int*   ei  = (const int*)d_in[2];   // [2][N_EDGES]: row0=src, row1=dst
    const float* W1  = (const float*)d_in[3];
    const float* b1  = (const float*)d_in[4];
    const float* W2  = (const float*)d_in[5];
    const float* b2  = (const float*)d_in[6];
    float* out = (float*)d_out;

    char* ws = (char*)d_ws;
    unsigned short* vb   = (unsigned short*)ws;                     // 12.8 MB (f16 v)
    unsigned short* qb   = (unsigned short*)(ws + 12800000);        // 12.8 MB (f16 -q)
    unsigned int* coarse = (unsigned int*)(ws + 25600000);          // 6.4 MB
    int*            dirT = (int*)(ws + 32000000);                   // 3.2 MB
    unsigned short* W2T  = (unsigned short*)(ws + 35200000);        // 8 KB (f16, transposed)

    const int* src = ei;
    const int* dst = ei + N_EDGES;

    hipLaunchKernelGGL(sort_kernel, dim3(B1), dim3(1024), 0, stream,
                       src, dst, coarse, dirT, W2, W2T);
    hipLaunchKernelGGL(node_kernel, dim3(NB_NODE), dim3(256), 0, stream,
                       x, pos, W1, b1, vb, qb);
    hipLaunchKernelGGL(agg_kernel, dim3(NBKT), dim3(256), 0, stream,
                       vb, qb, W2T, b2, dirT, coarse, out);
}

// Round 11
// 181.989 us; speedup vs baseline: 1.1875x; 1.0971x over previous
//
#include <hip/hip_runtime.h>
#include <math.h>

#define N_NODES 100000
#define N_EDGES 1600000
#define D_FEAT 32
#define D_HID 64
#define D_OUT 64
#define CAP 48          // per-node slot capacity; deg ~ Poisson(16), safe
#define NPB 32          // nodes per coarse bucket (1<<5); 3125*32 = 100000 exact
#define NBKT 3125       // N_NODES / NPB
#define B1 256          // sort blocks; each owns a dense 6250-entry segment
#define E_PER_B1 6250   // 256 * 6250 = 1.6M edges exactly
#define NTILE 64        // node-precompute tile (64 nodes staged in LDS)
#define NB_NODE 1563    // ceil(100000/64) node tiles, one block each

typedef _Float16 half8 __attribute__((ext_vector_type(8)));
typedef float f32x4  __attribute__((ext_vector_type(4)));

// packed f16 relu(v + (-q)) on a channel pair, guaranteed lowering:
// exactly one v_pk_add_f16 + one v_pk_max_f16.
__device__ inline unsigned pk_subrelu(unsigned v, unsigned nq) {
    unsigned r;
    asm("v_pk_add_f16 %0, %1, %2\n\t"
        "v_pk_max_f16 %0, %0, 0"
        : "=v"(r) : "v"(v), "v"(nq));
    return r;
}

// ---------------------------------------------------------------------------
// Kernel 1: per-node precompute (f32 math, f16 store, q stored NEGATED).
//   q[n][k] = pos[n] @ W1[32:35];  v[n][k] = b1[k] + x[n] @ W1[:32] + q[n][k]
// R10 lesson (accounting): node+sort ≈ 105-115us, bigger than agg. The old
// node loop loaded x via WAVE-UNIFORM addresses — 35 serial broadcast VMEM
// ops per node (pure latency chain). Now: 64-node x/pos tiles staged into
// LDS with COALESCED loads (8 KB/tile), per-node reads hit LDS broadcast.
// One tile per block, 1563 blocks (6.1 blocks/CU, 24 waves/CU).
// ---------------------------------------------------------------------------
__global__ __launch_bounds__(256)
void node_kernel(const float* __restrict__ x,
                 const float* __restrict__ pos,
                 const float* __restrict__ W1,
                 const float* __restrict__ b1,
                 unsigned short* __restrict__ vb,
                 unsigned short* __restrict__ qb) {
    __shared__ float xs[NTILE * D_FEAT];   // 8 KB
    __shared__ float ps[NTILE * 3];        // 768 B

    const int tid  = threadIdx.x;
    const int lane = tid & 63;
    const int wave = tid >> 6;

    const int n0  = blockIdx.x * NTILE;
    const int cnt = (N_NODES - n0 < NTILE) ? (N_NODES - n0) : NTILE;  // 64 or 32

    // coalesced staging
    for (int i = tid; i < cnt * D_FEAT; i += 256)
        xs[i] = x[(size_t)n0 * D_FEAT + i];
    for (int i = tid; i < cnt * 3; i += 256)
        ps[i] = pos[(size_t)n0 * 3 + i];

    float w[D_FEAT + 3];
#pragma unroll
    for (int f = 0; f < D_FEAT + 3; ++f)
        w[f] = W1[f * D_HID + lane];
    const float bb = b1[lane];
    __syncthreads();

    for (int ln = wave; ln < cnt; ln += 4) {
        const int node = n0 + ln;
        float acc = bb;
#pragma unroll
        for (int f = 0; f < D_FEAT; ++f)
            acc = fmaf(xs[ln * D_FEAT + f], w[f], acc);   // LDS broadcast reads

        float qa = 0.0f;
#pragma unroll
        for (int p = 0; p < 3; ++p)
            qa = fmaf(ps[ln * 3 + p], w[D_FEAT + p], qa);

        vb[(size_t)node * D_HID + lane] =
            __builtin_bit_cast(unsigned short, (_Float16)(acc + qa));
        qb[(size_t)node * D_HID + lane] =
            __builtin_bit_cast(unsigned short, (_Float16)(-qa));
    }
}

// ---------------------------------------------------------------------------
// Kernel 2: dense local counting sort + W2T build (block 0).
// R8->R10 lesson: the TRANSPOSED dirT write (3125 distinct lines per block,
// 800K scattered 4B RFOs) cost ~11us on the sort side — more than it saved
// in agg. Reverted to R6-style DENSE dir: dir[blk][b] is a contiguous
// 12.5 KB stream per block. agg's dir reads become scattered (256 x 4B,
// L2-resident) — the R6 best-total configuration.
// Entry packing: (src << 5) | (dst & 31).
// ---------------------------------------------------------------------------
__global__ __launch_bounds__(1024)
void sort_kernel(const int* __restrict__ src,
                 const int* __restrict__ dst,
                 unsigned int* __restrict__ coarse,
                 int* __restrict__ dir,
                 const float* __restrict__ W2,
                 unsigned short* __restrict__ W2T) {
    __shared__ int hist[NBKT];       // 12.5 KB: counts -> starts -> cursors
    __shared__ int stage[E_PER_B1];  // 25 KB
    __shared__ int wsum[16];

    const int tid  = threadIdx.x;
    const int lane = tid & 63;
    const int wv   = tid >> 6;       // 0..15
    const int e0   = blockIdx.x * E_PER_B1;

    if (blockIdx.x == 0) {           // f16 transpose of W2 (16 KB, L2-hot)
        for (int i = tid; i < D_HID * D_OUT; i += 1024) {
            float w = W2[i];                      // i = k*64 + n
            W2T[(size_t)(i & 63) * D_HID + (i >> 6)] =
                __builtin_bit_cast(unsigned short, (_Float16)w);
        }
    }

    for (int b = tid; b < NBKT; b += 1024) hist[b] = 0;
    __syncthreads();

    for (int e = e0 + tid; e < e0 + E_PER_B1; e += 1024)
        atomicAdd(&hist[dst[e] >> 5], 1);
    __syncthreads();

    // ---- exclusive scan of hist (3125) in place: 4 elems/thread ----
    const int i0 = tid * 4;
    int c[4];
    int sum = 0;
#pragma unroll
    for (int k = 0; k < 4; ++k) {
        c[k] = (i0 + k < NBKT) ? hist[i0 + k] : 0;
        sum += c[k];
    }
    int inc = sum;                       // wave-inclusive scan of chunk sums
#pragma unroll
    for (int d = 1; d < 64; d <<= 1) {
        int u = __shfl_up(inc, d, 64);
        if (lane >= d) inc += u;
    }
    if (lane == 63) wsum[wv] = inc;      // wave totals
    __syncthreads();
    if (wv == 0) {
        int s = (lane < 16) ? wsum[lane] : 0;
#pragma unroll
        for (int d = 1; d < 16; d <<= 1) {
            int u = __shfl_up(s, d, 64);
            if (lane >= d) s += u;
        }
        if (lane < 16) wsum[lane] = s;   // inclusive wave prefix
    }
    __syncthreads();
    int excl = inc - sum + ((wv > 0) ? wsum[wv - 1] : 0);
#pragma unroll
    for (int k = 0; k < 4; ++k) {
        if (i0 + k < NBKT) hist[i0 + k] = excl;   // own slots only: no race
        excl += c[k];
    }
    __syncthreads();

    // ---- dense directory: absolute start of each bucket in this segment
    for (int b = tid; b < NBKT; b += 1024)
        dir[(size_t)blockIdx.x * NBKT + b] = e0 + hist[b];
    __syncthreads();                     // dir written before cursors move

    // ---- placement via LDS cursors into LDS staging ----
    for (int e = e0 + tid; e < e0 + E_PER_B1; e += 1024) {
        int d = dst[e], s = src[e];
        int p = atomicAdd(&hist[d >> 5], 1);   // p in [0, 6250) by construction
        stage[p] = (int)(((unsigned)s << 5) | (unsigned)(d & 31));
    }
    __syncthreads();

    // ---- dense, full-line copy-out ----
    for (int i = tid; i < E_PER_B1; i += 1024)
        coarse[e0 + i] = (unsigned)stage[i];
}

// ---------------------------------------------------------------------------
// Kernel 3: fused fine-bucketing + per-node MFMA aggregation (R8-identical
// except dense-dir read; R10's upfront-issue fast path reverted — it was
// neutral-to-negative). 3125 blocks of 256 thr, 8 nodes/wave, W2T vector
// prologue, packed-f16 afrag, 4x2 mfma_f32_16x16x32_f16, register max.
// Padding rows use src = i (self-loop, idempotent under max).
// ---------------------------------------------------------------------------
__global__ __launch_bounds__(256)
void agg_kernel(const unsigned short* __restrict__ vb,
                const unsigned short* __restrict__ qb,
                const unsigned short* __restrict__ W2T,
                const float* __restrict__ b2,
                const int* __restrict__ dir,
                const unsigned int* __restrict__ coarse,
                float* __restrict__ out) {
    __shared__ int lcnt[NPB];
    __shared__ int lslots[NPB][CAP];

    const int tid  = threadIdx.x;
    const int lane = tid & 63;
    const int wave = tid >> 6;             // 0..3
    const int quad = lane >> 4;
    const int mrow = lane & 15;
    const int bkt  = blockIdx.x;
    const int nbase = bkt << 5;

    // B fragments: one 16B vector load each from W2T[n][k]
    half8 bfrag[4][2];
#pragma unroll
    for (int t = 0; t < 4; ++t)
#pragma unroll
        for (int kh = 0; kh < 2; ++kh)
            bfrag[t][kh] = *(const half8*)(W2T + (size_t)(t * 16 + mrow) * D_HID
                                               + kh * 32 + quad * 8);
    float bias[4];
#pragma unroll
    for (int t = 0; t < 4; ++t) bias[t] = b2[t * 16 + mrow];

    // fine bucketing into LDS: thread t walks sort-block t's segment.
    for (int i = tid; i < NPB; i += 256) lcnt[i] = 0;
    __syncthreads();
    {
        const int s0 = dir[(size_t)tid * NBKT + bkt];
        const int s1 = (bkt + 1 < NBKT) ? dir[(size_t)tid * NBKT + bkt + 1]
                                        : (tid + 1) * E_PER_B1;
        for (int j = s0; j < s1; ++j) {
            unsigned enc = coarse[j];
            int local = (int)(enc & 31u);
            int s     = (int)(enc >> 5);
            int p = atomicAdd(&lcnt[local], 1);
            if (p < CAP) lslots[local][p] = s;
        }
    }
    __syncthreads();

    // per-node aggregation, 8 nodes per wave
    for (int ln = wave; ln < NPB; ln += 4) {
        const int node = nbase + ln;       // 3125*32 == N_NODES: no bound check

        const uint4 nq0 = *(const uint4*)(qb + (size_t)node * D_HID + quad * 8);
        const uint4 nq1 = *(const uint4*)(qb + (size_t)node * D_HID + 32 + quad * 8);

        int deg = lcnt[ln];
        if (deg > CAP) deg = CAP;
        const int rows = deg + 1;              // + self-loop
        const int nbat = (rows + 15) >> 4;

        float rmax[4][4];
#pragma unroll
        for (int t = 0; t < 4; ++t)
#pragma unroll
            for (int r = 0; r < 4; ++r) rmax[t][r] = -INFINITY;

        for (int b = 0; b < nbat; ++b) {
            int idx = b * 16 + mrow;
            int idxc = (idx < CAP) ? idx : (CAP - 1);    // clamp LDS read
            int s = (idx < deg) ? lslots[ln][idxc] : node;

            const uint4 v0 = *(const uint4*)(vb + (size_t)s * D_HID + quad * 8);
            const uint4 v1 = *(const uint4*)(vb + (size_t)s * D_HID + 32 + quad * 8);

            uint4 a0u, a1u;
            a0u.x = pk_subrelu(v0.x, nq0.x);
            a0u.y = pk_subrelu(v0.y, nq0.y);
            a0u.z = pk_subrelu(v0.z, nq0.z);
            a0u.w = pk_subrelu(v0.w, nq0.w);
            a1u.x = pk_subrelu(v1.x, nq1.x);
            a1u.y = pk_subrelu(v1.y, nq1.y);
            a1u.z = pk_subrelu(v1.z, nq1.z);
            a1u.w = pk_subrelu(v1.w, nq1.w);
            half8 a0 = __builtin_bit_cast(half8, a0u);
            half8 a1 = __builtin_bit_cast(half8, a1u);

#pragma unroll
            for (int t = 0; t < 4; ++t) {
                f32x4 acc = (f32x4){0.f, 0.f, 0.f, 0.f};
                acc = __builtin_amdgcn_mfma_f32_16x16x32_f16(a0, bfrag[t][0], acc, 0, 0, 0);
                acc = __builtin_amdgcn_mfma_f32_16x16x32_f16(a1, bfrag[t][1], acc, 0, 0, 0);
#pragma unroll
                for (int r = 0; r < 4; ++r)
                    rmax[t][r] = fmaxf(rmax[t][r], acc[r]);
            }
        }

        float fin[4];
#pragma unroll
        for (int t = 0; t < 4; ++t) {
            float m = fmaxf(fmaxf(rmax[t][0], rmax[t][1]), fmaxf(rmax[t][2], rmax[t][3]));
            m = fmaxf(m, __shfl_xor(m, 16, 64));
            m = fmaxf(m, __shfl_xor(m, 32, 64));
            fin[t] = m + bias[t];
        }
        float r = (quad == 0) ? fin[0] : (quad == 1) ? fin[1] : (quad == 2) ? fin[2] : fin[3];
        out[(size_t)node * D_OUT + lane] = r;
    }
}

// ---------------------------------------------------------------------------
extern "C" void kernel_launch(void* const* d_in, const int* in_sizes, int n_in,
                              void* d_out, int out_size, void* d_ws, size_t ws_size,
                              hipStream_t stream) {
    const float* x   = (const float*)d_in[0];
    const float* pos = (const float*)d_in[1];
    const int*   ei  = (const int*)d_in[2];   // [2][N_EDGES]: row0=src, row1=dst
    const float* W1  = (const float*)d_in[3];
    const float* b1  = (const float*)d_in[4];
    const float* W2  = (const float*)d_in[5];
    const float* b2  = (const float*)d_in[6];
    float* out = (float*)d_out;

    char* ws = (char*)d_ws;
    unsigned short* vb   = (unsigned short*)ws;                     // 12.8 MB (f16 v)
    unsigned short* qb   = (unsigned short*)(ws + 12800000);        // 12.8 MB (f16 -q)
    unsigned int* coarse = (unsigned int*)(ws + 25600000);          // 6.4 MB
    int*            dir  = (int*)(ws + 32000000);                   // 3.2 MB
    unsigned short* W2T  = (unsigned short*)(ws + 35200000);        // 8 KB (f16, transposed)

    const int* src = ei;
    const int* dst = ei + N_EDGES;

    hipLaunchKernelGGL(sort_kernel, dim3(B1), dim3(1024), 0, stream,
                       src, dst, coarse, dir, W2, W2T);
    hipLaunchKernelGGL(node_kernel, dim3(NB_NODE), dim3(256), 0, stream,
                       x, pos, W1, b1, vb, qb);
    hipLaunchKernelGGL(agg_kernel, dim3(NBKT), dim3(256), 0, stream,
                       vb, qb, W2T, b2, dir, coarse, out);
}